// Round 4
// baseline (442.116 us; speedup 1.0000x reference)
//
#include <hip/hip_runtime.h>

#define HID 64
#define SCAN_BLOCK 256
#define SCAN_ITEMS 16
#define SCAN_TILE (SCAN_BLOCK * SCAN_ITEMS)   // 4096 elements per block

// x[n][h] = emb[z[n]][h]
__global__ void embed_kernel(const int* __restrict__ z, const float* __restrict__ emb,
                             float* __restrict__ x, int n) {
    int t = blockIdx.x * blockDim.x + threadIdx.x;
    if (t >= n * HID) return;
    int node = t >> 6, h = t & 63;
    x[t] = emb[z[node] * HID + h];
}

// deg[row[e]]++  — 4 edges/thread via int4; atomics are fire-and-forget so the
// batching mainly amortizes the coalesced index load.
__global__ void hist_kernel(const int* __restrict__ row, int* __restrict__ deg, int e) {
    int t = blockIdx.x * blockDim.x + threadIdx.x;
    int base = t * 4;
    if (base >= e) return;
    if (base + 3 < e) {
        int4 r4 = *(const int4*)(row + base);
        atomicAdd(&deg[r4.x], 1);
        atomicAdd(&deg[r4.y], 1);
        atomicAdd(&deg[r4.z], 1);
        atomicAdd(&deg[r4.w], 1);
    } else {
        for (int i = base; i < e; ++i) atomicAdd(&deg[row[i]], 1);
    }
}

// ---- 3-phase exclusive scan of deg[0..n1) into offs[0..n1) ----
__global__ void scanA_kernel(const int* __restrict__ deg, int* __restrict__ offs,
                             int* __restrict__ bsums, int n1) {
    __shared__ int wsum[SCAN_BLOCK / 64];
    int tid  = threadIdx.x;
    int lane = tid & 63, w = tid >> 6;
    int tbase = blockIdx.x * SCAN_TILE + tid * SCAN_ITEMS;

    int vals[SCAN_ITEMS];
    int s = 0;
#pragma unroll
    for (int i = 0; i < SCAN_ITEMS; ++i) {
        int idx = tbase + i;
        vals[i] = (idx < n1) ? deg[idx] : 0;
        s += vals[i];
    }
    int sc = s;
#pragma unroll
    for (int d = 1; d < 64; d <<= 1) {
        int t2 = __shfl_up(sc, d);
        if (lane >= d) sc += t2;
    }
    if (lane == 63) wsum[w] = sc;
    __syncthreads();
    int woff = 0;
    for (int i = 0; i < w; ++i) woff += wsum[i];
    int texcl = woff + sc - s;
    if (tid == 0) {
        int tot = 0;
        for (int i = 0; i < SCAN_BLOCK / 64; ++i) tot += wsum[i];
        bsums[blockIdx.x] = tot;
    }
    int run = 0;
#pragma unroll
    for (int i = 0; i < SCAN_ITEMS; ++i) {
        int idx = tbase + i;
        if (idx < n1) offs[idx] = texcl + run;
        run += vals[i];
    }
}

__global__ void scanB_kernel(int* __restrict__ bsums, int nb) {
    __shared__ int wsum[SCAN_BLOCK / 64];
    __shared__ int chunk_tot;
    int tid = threadIdx.x, lane = tid & 63, w = tid >> 6;
    int carry = 0;
    for (int base = 0; base < nb; base += SCAN_BLOCK) {
        int idx = base + tid;
        int v = (idx < nb) ? bsums[idx] : 0;
        int sc = v;
#pragma unroll
        for (int d = 1; d < 64; d <<= 1) {
            int t2 = __shfl_up(sc, d);
            if (lane >= d) sc += t2;
        }
        if (lane == 63) wsum[w] = sc;
        __syncthreads();
        int woff = 0;
        for (int i = 0; i < w; ++i) woff += wsum[i];
        if (idx < nb) bsums[idx] = carry + woff + sc - v;
        if (tid == SCAN_BLOCK - 1) chunk_tot = woff + sc;
        __syncthreads();
        carry += chunk_tot;
        __syncthreads();
    }
}

__global__ void scanC_kernel(int* __restrict__ offs, const int* __restrict__ bsums, int n1) {
    int t = blockIdx.x * blockDim.x + threadIdx.x;
    if (t < n1) offs[t] += bsums[t / SCAN_TILE];
}

// CSR fill + fused rbf. 4 edges/thread: int4 index loads, 4 independent
// rbf computations, then 4 independent atomicAdd chains, then 4 stores —
// breaks the 1-outstanding-chain-per-lane serialization of the 1-edge version.
__global__ void fill_kernel(const int* __restrict__ row, const int* __restrict__ col,
                            const float* __restrict__ pos, int* __restrict__ cursor,
                            int2* __restrict__ ecr, int e) {
    int t = blockIdx.x * blockDim.x + threadIdx.x;
    int base = t * 4;
    if (base >= e) return;
    if (base + 3 < e) {
        int4 r4 = *(const int4*)(row + base);
        int4 c4 = *(const int4*)(col + base);
        int rs[4] = {r4.x, r4.y, r4.z, r4.w};
        int cs[4] = {c4.x, c4.y, c4.z, c4.w};
        float rb[4];
#pragma unroll
        for (int i = 0; i < 4; ++i) {
            int r = rs[i], c = cs[i];
            float dx = pos[3 * r]     - pos[3 * c];
            float dy = pos[3 * r + 1] - pos[3 * c + 1];
            float dz = pos[3 * r + 2] - pos[3 * c + 2];
            rb[i] = expf(-sqrtf(dx * dx + dy * dy + dz * dz));
        }
        int p[4];
#pragma unroll
        for (int i = 0; i < 4; ++i) p[i] = atomicAdd(&cursor[rs[i]], 1);
#pragma unroll
        for (int i = 0; i < 4; ++i) ecr[p[i]] = make_int2(cs[i], __float_as_int(rb[i]));
    } else {
        for (int i = base; i < e; ++i) {
            int r = row[i], c = col[i];
            float dx = pos[3 * r]     - pos[3 * c];
            float dy = pos[3 * r + 1] - pos[3 * c + 1];
            float dz = pos[3 * r + 2] - pos[3 * c + 2];
            float rbf = expf(-sqrtf(dx * dx + dy * dy + dz * dz));
            int p = atomicAdd(&cursor[r], 1);
            ecr[p] = make_int2(c, __float_as_int(rbf));
        }
    }
}

// y[n] = x[n] + sum_{edges (n,c)} x[c] * rbf
// One wave per node, lane = h. 64 edge records loaded in ONE coalesced vector
// load (lane = edge slot), broadcast via __shfl; 8 independent row loads in
// flight per wave.
__global__ void gather_kernel(const float* __restrict__ x, const int* __restrict__ offs,
                              const int2* __restrict__ ecr, float* __restrict__ y, int n) {
    int lane = threadIdx.x & 63;
    int wid = (blockIdx.x * blockDim.x + threadIdx.x) >> 6;
    int nw = (gridDim.x * blockDim.x) >> 6;
    for (int node = wid; node < n; node += nw) {
        int nu = __builtin_amdgcn_readfirstlane(node);
        int beg = offs[nu], end = offs[nu + 1];
        float acc = x[nu * HID + lane];
        for (int cbeg = beg; cbeg < end; cbeg += 64) {
            int m = end - cbeg; if (m > 64) m = 64;
            int2 cr = (lane < m) ? ecr[cbeg + lane] : make_int2(0, 0);
            int cc = cr.x;
            float rr = __int_as_float(cr.y);
            int j = 0;
            for (; j + 8 <= m; j += 8) {
                int   c0 = __shfl(cc, j);     float r0 = __shfl(rr, j);
                int   c1 = __shfl(cc, j + 1); float r1 = __shfl(rr, j + 1);
                int   c2 = __shfl(cc, j + 2); float r2 = __shfl(rr, j + 2);
                int   c3 = __shfl(cc, j + 3); float r3 = __shfl(rr, j + 3);
                int   c4 = __shfl(cc, j + 4); float r4 = __shfl(rr, j + 4);
                int   c5 = __shfl(cc, j + 5); float r5 = __shfl(rr, j + 5);
                int   c6 = __shfl(cc, j + 6); float r6 = __shfl(rr, j + 6);
                int   c7 = __shfl(cc, j + 7); float r7 = __shfl(rr, j + 7);
                float x0 = x[c0 * HID + lane];
                float x1 = x[c1 * HID + lane];
                float x2 = x[c2 * HID + lane];
                float x3 = x[c3 * HID + lane];
                float x4 = x[c4 * HID + lane];
                float x5 = x[c5 * HID + lane];
                float x6 = x[c6 * HID + lane];
                float x7 = x[c7 * HID + lane];
                acc = fmaf(x0, r0, acc);
                acc = fmaf(x1, r1, acc);
                acc = fmaf(x2, r2, acc);
                acc = fmaf(x3, r3, acc);
                acc = fmaf(x4, r4, acc);
                acc = fmaf(x5, r5, acc);
                acc = fmaf(x6, r6, acc);
                acc = fmaf(x7, r7, acc);
            }
            for (; j < m; ++j) {
                int   c0 = __shfl(cc, j);
                float r0 = __shfl(rr, j);
                acc = fmaf(x[c0 * HID + lane], r0, acc);
            }
        }
        y[nu * HID + lane] = acc;
    }
}

// out[n][h] = relu(b[h] + sum_k y[n][k] * W[h][k])
// One wave, lane h keeps W row h in VGPRs; TWO nodes per iteration so two
// independent uniform-row load + FMA chains overlap (single-node version
// exposes the full serial row-load latency per node).
__global__ void linear_kernel(const float* __restrict__ x, const float* __restrict__ W,
                              const float* __restrict__ b, float* __restrict__ out, int n) {
    int h = threadIdx.x & 63;
    int wid = (blockIdx.x * blockDim.x + threadIdx.x) >> 6;
    int nw = (gridDim.x * blockDim.x) >> 6;
    float w[HID];
#pragma unroll
    for (int k = 0; k < HID; ++k) w[k] = W[h * HID + k];
    float bias = b[h];
    for (int p = wid; 2 * p < n; p += nw) {
        int n0 = __builtin_amdgcn_readfirstlane(2 * p);
        int n1 = n0 + 1;
        const float* x0 = x + (size_t)n0 * HID;
        float acc0 = bias;
        if (n1 < n) {
            const float* x1 = x + (size_t)n1 * HID;
            float acc1 = bias;
#pragma unroll
            for (int k = 0; k < HID; ++k) {
                acc0 = fmaf(x0[k], w[k], acc0);
                acc1 = fmaf(x1[k], w[k], acc1);
            }
            out[(size_t)n0 * HID + h] = fmaxf(acc0, 0.0f);
            out[(size_t)n1 * HID + h] = fmaxf(acc1, 0.0f);
        } else {
#pragma unroll
            for (int k = 0; k < HID; ++k) acc0 = fmaf(x0[k], w[k], acc0);
            out[(size_t)n0 * HID + h] = fmaxf(acc0, 0.0f);
        }
    }
}

extern "C" void kernel_launch(void* const* d_in, const int* in_sizes, int n_in,
                              void* d_out, int out_size, void* d_ws, size_t ws_size,
                              hipStream_t stream) {
    const int*   z    = (const int*)d_in[0];
    const float* pos  = (const float*)d_in[1];
    const int*   eidx = (const int*)d_in[2];
    const float* emb  = (const float*)d_in[3];
    const float* Ws   = (const float*)d_in[4];
    const float* bs   = (const float*)d_in[5];
    int n = in_sizes[0];
    int e = in_sizes[2] / 2;
    int nlayers = in_sizes[4] / (HID * HID);
    const int* row = eidx;
    const int* col = eidx + e;
    float* out = (float*)d_out;

    char* ws = (char*)d_ws;
    float* A      = (float*)ws;                               // n*64 floats (25.6 MB)
    int2*  ecr    = (int2*)(ws + (size_t)n * HID * 4);        // e int2 (8 MB)
    int*   deg    = (int*)((char*)ecr + (size_t)e * 8);
    int*   offs   = deg + (n + 1);
    int*   cursor = offs + (n + 1);
    int*   bsums  = cursor + (n + 1);

    int n1 = n + 1;
    int nb = (n1 + SCAN_TILE - 1) / SCAN_TILE;
    int e4 = (e + 3) / 4;

    hipMemsetAsync(deg, 0, n1 * sizeof(int), stream);
    embed_kernel<<<(n * HID + 255) / 256, 256, 0, stream>>>(z, emb, A, n);
    hist_kernel<<<(e4 + 255) / 256, 256, 0, stream>>>(row, deg, e);
    scanA_kernel<<<nb, SCAN_BLOCK, 0, stream>>>(deg, offs, bsums, n1);
    scanB_kernel<<<1, SCAN_BLOCK, 0, stream>>>(bsums, nb);
    scanC_kernel<<<(n1 + 255) / 256, 256, 0, stream>>>(offs, bsums, n1);
    hipMemcpyAsync(cursor, offs, n * sizeof(int), hipMemcpyDeviceToDevice, stream);
    fill_kernel<<<(e4 + 255) / 256, 256, 0, stream>>>(row, col, pos, cursor, ecr, e);

    for (int l = 0; l < nlayers; ++l) {
        gather_kernel<<<2048, 256, 0, stream>>>(A, offs, ecr, out, n);
        float* dst = (l == nlayers - 1) ? out : A;
        linear_kernel<<<1024, 256, 0, stream>>>(out, Ws + (size_t)l * HID * HID,
                                                bs + (size_t)l * HID, dst, n);
    }
}

// Round 5
// 413.272 us; speedup vs baseline: 1.0698x; 1.0698x over previous
//
#include <hip/hip_runtime.h>
#include <hip/hip_fp16.h>
#include <hip/hip_bf16.h>

#define HID 64
#define SCAN_BLOCK 256
#define SCAN_ITEMS 16
#define SCAN_TILE (SCAN_BLOCK * SCAN_ITEMS)   // 4096 elements per block

__device__ __forceinline__ unsigned short f32_to_bf16_bits(float f) {
    unsigned u = __float_as_uint(f);
    unsigned r = (u + 0x7fff + ((u >> 16) & 1)) >> 16;   // round-to-nearest-even
    return (unsigned short)r;
}
__device__ __forceinline__ float bf16_bits_to_f32(unsigned short b) {
    return __uint_as_float((unsigned)b << 16);
}

// x[n][h] = emb[z[n]][h]; also writes bf16 shadow copy for gather's neighbor reads
__global__ void embed_kernel(const int* __restrict__ z, const float* __restrict__ emb,
                             float* __restrict__ x, unsigned short* __restrict__ x16, int n) {
    int t = blockIdx.x * blockDim.x + threadIdx.x;
    if (t >= n * HID) return;
    int node = t >> 6, h = t & 63;
    float v = emb[z[node] * HID + h];
    x[t] = v;
    x16[t] = f32_to_bf16_bits(v);
}

// deg[row[e]]++  (1 edge/thread — max parallelism; R4 showed batching hurts here)
__global__ void hist_kernel(const int* __restrict__ row, int* __restrict__ deg, int e) {
    int t = blockIdx.x * blockDim.x + threadIdx.x;
    if (t < e) atomicAdd(&deg[row[t]], 1);
}

// ---- 3-phase exclusive scan of deg[0..n1) into offs[0..n1) ----
__global__ void scanA_kernel(const int* __restrict__ deg, int* __restrict__ offs,
                             int* __restrict__ bsums, int n1) {
    __shared__ int wsum[SCAN_BLOCK / 64];
    int tid  = threadIdx.x;
    int lane = tid & 63, w = tid >> 6;
    int tbase = blockIdx.x * SCAN_TILE + tid * SCAN_ITEMS;

    int vals[SCAN_ITEMS];
    int s = 0;
#pragma unroll
    for (int i = 0; i < SCAN_ITEMS; ++i) {
        int idx = tbase + i;
        vals[i] = (idx < n1) ? deg[idx] : 0;
        s += vals[i];
    }
    int sc = s;
#pragma unroll
    for (int d = 1; d < 64; d <<= 1) {
        int t2 = __shfl_up(sc, d);
        if (lane >= d) sc += t2;
    }
    if (lane == 63) wsum[w] = sc;
    __syncthreads();
    int woff = 0;
    for (int i = 0; i < w; ++i) woff += wsum[i];
    int texcl = woff + sc - s;
    if (tid == 0) {
        int tot = 0;
        for (int i = 0; i < SCAN_BLOCK / 64; ++i) tot += wsum[i];
        bsums[blockIdx.x] = tot;
    }
    int run = 0;
#pragma unroll
    for (int i = 0; i < SCAN_ITEMS; ++i) {
        int idx = tbase + i;
        if (idx < n1) offs[idx] = texcl + run;
        run += vals[i];
    }
}

__global__ void scanB_kernel(int* __restrict__ bsums, int nb) {
    __shared__ int wsum[SCAN_BLOCK / 64];
    __shared__ int chunk_tot;
    int tid = threadIdx.x, lane = tid & 63, w = tid >> 6;
    int carry = 0;
    for (int base = 0; base < nb; base += SCAN_BLOCK) {
        int idx = base + tid;
        int v = (idx < nb) ? bsums[idx] : 0;
        int sc = v;
#pragma unroll
        for (int d = 1; d < 64; d <<= 1) {
            int t2 = __shfl_up(sc, d);
            if (lane >= d) sc += t2;
        }
        if (lane == 63) wsum[w] = sc;
        __syncthreads();
        int woff = 0;
        for (int i = 0; i < w; ++i) woff += wsum[i];
        if (idx < nb) bsums[idx] = carry + woff + sc - v;
        if (tid == SCAN_BLOCK - 1) chunk_tot = woff + sc;
        __syncthreads();
        carry += chunk_tot;
        __syncthreads();
    }
}

__global__ void scanC_kernel(int* __restrict__ offs, const int* __restrict__ bsums, int n1) {
    int t = blockIdx.x * blockDim.x + threadIdx.x;
    if (t < n1) offs[t] += bsums[t / SCAN_TILE];
}

// CSR fill + fused rbf, PACKED 4-byte record: (col << 15) | fp16(rbf) sans sign.
// col < 2^17 (N=100k), rbf in (0,1] so fp16 sign bit is always 0.
// Halves the scattered-store dirty-line traffic (the measured fill bottleneck:
// WRITE_SIZE 65 MB for an 8 MB array in R4).
__global__ void fill_kernel(const int* __restrict__ row, const int* __restrict__ col,
                            const float* __restrict__ pos, int* __restrict__ cursor,
                            unsigned* __restrict__ ecr, int e) {
    int t = blockIdx.x * blockDim.x + threadIdx.x;
    if (t >= e) return;
    int r = row[t], c = col[t];
    float dx = pos[3 * r]     - pos[3 * c];
    float dy = pos[3 * r + 1] - pos[3 * c + 1];
    float dz = pos[3 * r + 2] - pos[3 * c + 2];
    float rbf = expf(-sqrtf(dx * dx + dy * dy + dz * dz));
    unsigned short hb = __half_as_ushort(__float2half(rbf));   // sign bit = 0
    int p = atomicAdd(&cursor[r], 1);
    ecr[p] = ((unsigned)c << 15) | (unsigned)hb;
}

// y[n] = x[n] + sum_{edges (n,c)} bf16(x[c]) * rbf
// One wave per node, lane = h. 64 packed edge words per coalesced load,
// ONE shfl broadcast per edge (word decoded after broadcast); neighbor rows
// read from the bf16 shadow (128 B/row vs 256 B) — halves L2-miss traffic.
__global__ void gather_kernel(const float* __restrict__ x, const unsigned short* __restrict__ x16,
                              const int* __restrict__ offs, const unsigned* __restrict__ ecr,
                              float* __restrict__ y, int n) {
    int lane = threadIdx.x & 63;
    int wid = (blockIdx.x * blockDim.x + threadIdx.x) >> 6;
    int nw = (gridDim.x * blockDim.x) >> 6;
    for (int node = wid; node < n; node += nw) {
        int nu = __builtin_amdgcn_readfirstlane(node);
        int beg = offs[nu], end = offs[nu + 1];
        float acc = x[nu * HID + lane];                 // residual in fp32
        for (int cbeg = beg; cbeg < end; cbeg += 64) {
            int m = end - cbeg; if (m > 64) m = 64;
            unsigned wrd = (lane < m) ? ecr[cbeg + lane] : 0u;
            int j = 0;
            for (; j + 8 <= m; j += 8) {
                unsigned w0 = __shfl(wrd, j);
                unsigned w1 = __shfl(wrd, j + 1);
                unsigned w2 = __shfl(wrd, j + 2);
                unsigned w3 = __shfl(wrd, j + 3);
                unsigned w4 = __shfl(wrd, j + 4);
                unsigned w5 = __shfl(wrd, j + 5);
                unsigned w6 = __shfl(wrd, j + 6);
                unsigned w7 = __shfl(wrd, j + 7);
                float v0 = bf16_bits_to_f32(x16[(w0 >> 15) * HID + lane]);
                float v1 = bf16_bits_to_f32(x16[(w1 >> 15) * HID + lane]);
                float v2 = bf16_bits_to_f32(x16[(w2 >> 15) * HID + lane]);
                float v3 = bf16_bits_to_f32(x16[(w3 >> 15) * HID + lane]);
                float v4 = bf16_bits_to_f32(x16[(w4 >> 15) * HID + lane]);
                float v5 = bf16_bits_to_f32(x16[(w5 >> 15) * HID + lane]);
                float v6 = bf16_bits_to_f32(x16[(w6 >> 15) * HID + lane]);
                float v7 = bf16_bits_to_f32(x16[(w7 >> 15) * HID + lane]);
                acc = fmaf(v0, __half2float(__ushort_as_half((unsigned short)(w0 & 0x7fff))), acc);
                acc = fmaf(v1, __half2float(__ushort_as_half((unsigned short)(w1 & 0x7fff))), acc);
                acc = fmaf(v2, __half2float(__ushort_as_half((unsigned short)(w2 & 0x7fff))), acc);
                acc = fmaf(v3, __half2float(__ushort_as_half((unsigned short)(w3 & 0x7fff))), acc);
                acc = fmaf(v4, __half2float(__ushort_as_half((unsigned short)(w4 & 0x7fff))), acc);
                acc = fmaf(v5, __half2float(__ushort_as_half((unsigned short)(w5 & 0x7fff))), acc);
                acc = fmaf(v6, __half2float(__ushort_as_half((unsigned short)(w6 & 0x7fff))), acc);
                acc = fmaf(v7, __half2float(__ushort_as_half((unsigned short)(w7 & 0x7fff))), acc);
            }
            for (; j < m; ++j) {
                unsigned w0 = __shfl(wrd, j);
                float v0 = bf16_bits_to_f32(x16[(w0 >> 15) * HID + lane]);
                acc = fmaf(v0, __half2float(__ushort_as_half((unsigned short)(w0 & 0x7fff))), acc);
            }
        }
        y[nu * HID + lane] = acc;
    }
}

// out[n][h] = relu(b[h] + sum_k y[n][k] * W[h][k]); lane h holds W row h.
// Two nodes/iter for ILP; optionally writes the bf16 shadow for the next
// layer's gather (out16 == nullptr on the final layer).
__global__ void linear_kernel(const float* __restrict__ x, const float* __restrict__ W,
                              const float* __restrict__ b, float* __restrict__ out,
                              unsigned short* __restrict__ out16, int n) {
    int h = threadIdx.x & 63;
    int wid = (blockIdx.x * blockDim.x + threadIdx.x) >> 6;
    int nw = (gridDim.x * blockDim.x) >> 6;
    float w[HID];
#pragma unroll
    for (int k = 0; k < HID; ++k) w[k] = W[h * HID + k];
    float bias = b[h];
    for (int p = wid; 2 * p < n; p += nw) {
        int n0 = __builtin_amdgcn_readfirstlane(2 * p);
        int n1 = n0 + 1;
        const float* x0 = x + (size_t)n0 * HID;
        float acc0 = bias;
        if (n1 < n) {
            const float* x1 = x + (size_t)n1 * HID;
            float acc1 = bias;
#pragma unroll
            for (int k = 0; k < HID; ++k) {
                acc0 = fmaf(x0[k], w[k], acc0);
                acc1 = fmaf(x1[k], w[k], acc1);
            }
            acc0 = fmaxf(acc0, 0.0f);
            acc1 = fmaxf(acc1, 0.0f);
            out[(size_t)n0 * HID + h] = acc0;
            out[(size_t)n1 * HID + h] = acc1;
            if (out16) {
                out16[(size_t)n0 * HID + h] = f32_to_bf16_bits(acc0);
                out16[(size_t)n1 * HID + h] = f32_to_bf16_bits(acc1);
            }
        } else {
#pragma unroll
            for (int k = 0; k < HID; ++k) acc0 = fmaf(x0[k], w[k], acc0);
            acc0 = fmaxf(acc0, 0.0f);
            out[(size_t)n0 * HID + h] = acc0;
            if (out16) out16[(size_t)n0 * HID + h] = f32_to_bf16_bits(acc0);
        }
    }
}

extern "C" void kernel_launch(void* const* d_in, const int* in_sizes, int n_in,
                              void* d_out, int out_size, void* d_ws, size_t ws_size,
                              hipStream_t stream) {
    const int*   z    = (const int*)d_in[0];
    const float* pos  = (const float*)d_in[1];
    const int*   eidx = (const int*)d_in[2];
    const float* emb  = (const float*)d_in[3];
    const float* Ws   = (const float*)d_in[4];
    const float* bs   = (const float*)d_in[5];
    int n = in_sizes[0];
    int e = in_sizes[2] / 2;
    int nlayers = in_sizes[4] / (HID * HID);
    const int* row = eidx;
    const int* col = eidx + e;
    float* out = (float*)d_out;

    char* ws = (char*)d_ws;
    float*          A      = (float*)ws;                            // n*64 f32   (25.6 MB)
    unsigned short* A16    = (unsigned short*)(ws + (size_t)n * HID * 4);      // n*64 bf16 (12.8 MB)
    unsigned*       ecr    = (unsigned*)((char*)A16 + (size_t)n * HID * 2);    // e u32      (4 MB)
    int*            deg    = (int*)((char*)ecr + (size_t)e * 4);
    int*            offs   = deg + (n + 1);
    int*            cursor = offs + (n + 1);
    int*            bsums  = cursor + (n + 1);

    int n1 = n + 1;
    int nb = (n1 + SCAN_TILE - 1) / SCAN_TILE;

    hipMemsetAsync(deg, 0, n1 * sizeof(int), stream);
    embed_kernel<<<(n * HID + 255) / 256, 256, 0, stream>>>(z, emb, A, A16, n);
    hist_kernel<<<(e + 255) / 256, 256, 0, stream>>>(row, deg, e);
    scanA_kernel<<<nb, SCAN_BLOCK, 0, stream>>>(deg, offs, bsums, n1);
    scanB_kernel<<<1, SCAN_BLOCK, 0, stream>>>(bsums, nb);
    scanC_kernel<<<(n1 + 255) / 256, 256, 0, stream>>>(offs, bsums, n1);
    hipMemcpyAsync(cursor, offs, n * sizeof(int), hipMemcpyDeviceToDevice, stream);
    fill_kernel<<<(e + 255) / 256, 256, 0, stream>>>(row, col, pos, cursor, ecr, e);

    for (int l = 0; l < nlayers; ++l) {
        gather_kernel<<<2048, 256, 0, stream>>>(A, A16, offs, ecr, out, n);
        float* dst = (l == nlayers - 1) ? out : A;
        unsigned short* dst16 = (l == nlayers - 1) ? nullptr : A16;
        linear_kernel<<<1024, 256, 0, stream>>>(out, Ws + (size_t)l * HID * HID,
                                                bs + (size_t)l * HID, dst, dst16, n);
    }
}